// Round 2
// baseline (350.007 us; speedup 1.0000x reference)
//
#include <hip/hip_runtime.h>
#include <hip/hip_bf16.h>
#include <math.h>

#define NROWS 8192
#define DDIM  4096
#define NEXP  64
#define KSPLIT 16
#define KCHUNK (DDIM / KSPLIT)   // 256
#define KSTEPS (KCHUNK / 32)     // 8  -- compile-time: allocator pipelines it

typedef __attribute__((ext_vector_type(8))) short bf16x8;
typedef __attribute__((ext_vector_type(4))) float f32x4;

__device__ inline unsigned short bf16_rne(float f) {
    unsigned u = __builtin_bit_cast(unsigned, f);
    u += 0x7FFF + ((u >> 16) & 1);
    return (unsigned short)(u >> 16);
}

// split 8 fp32 -> hi/lo bf16 (x = hi + lo + r, |r| <= 2^-18|x|)
__device__ inline void split8(const float* xf, bf16x8& hi, bf16x8& lo) {
#pragma unroll
    for (int j = 0; j < 8; j++) {
        const unsigned short h = bf16_rne(xf[j]);
        const float hf = __builtin_bit_cast(float, (unsigned)h << 16);
        hi[j] = (short)h;
        lo[j] = (short)bf16_rne(xf[j] - hf);
    }
}

// Preconvert W (64 x 4096 fp32) into MFMA B-fragment-linear bf16 hi/lo:
// frag elem j of lane l, tile t, k-chunk kc = B[k=kc*32+(l>>4)*8+j][n=t*16+(l&15)]
// at ((kc*4+t)*64+l)*8. ~1 MB total -> L2/L3-resident for the GEMM.
// ALSO zeroes the 2 MB logits accumulator and the 64 row-block completion
// counters (ws is poisoned every iteration; wfrag completes before the GEMM
// starts, so this is the race-free place to init both).
__global__ __launch_bounds__(256) void wfrag_kernel(
    const float* __restrict__ w, unsigned short* __restrict__ whi,
    unsigned short* __restrict__ wlo, float* __restrict__ logits,
    unsigned* __restrict__ cnt)
{
    const int kc = blockIdx.x;            // 0..127
    const int t  = threadIdx.x >> 6;      // n-tile 0..3
    const int l  = threadIdx.x & 63;
    const int e  = t * 16 + (l & 15);
    const int k0 = kc * 32 + ((l >> 4) * 8);
    const float* p = w + (size_t)e * DDIM + k0;
    float xf[8];
    *(float4*)&xf[0] = *(const float4*)p;
    *(float4*)&xf[4] = *(const float4*)(p + 4);
    bf16x8 hi, lo;
    split8(xf, hi, lo);
    const size_t off = ((size_t)(kc * 4 + t) * 64 + l) * 8;
    *(bf16x8*)(whi + off) = hi;
    *(bf16x8*)(wlo + off) = lo;

    // zero logits: 8192*64 floats = 131072 float4; 128 blk * 256 thr * 4 = 131072
    const float4 z = {0.f, 0.f, 0.f, 0.f};
    float4* lz = (float4*)logits;
    const int base = (blockIdx.x * 256 + threadIdx.x) * 4;
#pragma unroll
    for (int j = 0; j < 4; j++) lz[base + j] = z;

    if (blockIdx.x == 0 && threadIdx.x < 64) cnt[threadIdx.x] = 0;
}

// GEMM + fused gate. Block = 4 waves; wave = 32 rows (2 m-tiles) x 64 experts.
// Main loop unchanged from the passing R1 kernel (all trip counts compile-time,
// ~124 VGPR live set). Epilogue: HW f32 atomics into the 2 MB logits buffer.
// Then split-K completion counting: the LAST kh-block to finish a 128-row
// row-block performs the gate (sigmoid -> +bias -> top-2 -> normalize) for
// those rows, reading logits with AGENT-scope atomic loads (cross-XCD
// coherent point -- plain loads could see another XCD's stale line). This
// removes the separate gate_topk dispatch and its full-device drain; gate
// work for early row-blocks overlaps the GEMM tail.
__global__ __launch_bounds__(256) void gemm_gate_kernel(
    const float* __restrict__ x, const unsigned short* __restrict__ whi,
    const unsigned short* __restrict__ wlo, const float* __restrict__ bias,
    float* __restrict__ logits, unsigned* __restrict__ cnt,
    float* __restrict__ out)
{
    __shared__ bool last_flag;

    const int tid = threadIdx.x;
    const int wv  = tid >> 6;
    const int l   = tid & 63;
    const int q   = l >> 4;
    const int col = l & 15;
    const int r0  = blockIdx.x * 128 + wv * 32;
    const int kh  = blockIdx.y;
    const int kb  = kh * KCHUNK;

    const float* xp0 = x + (size_t)(r0 + col) * DDIM + kb + q * 8;
    const float* xp1 = xp0 + (size_t)16 * DDIM;
    const unsigned short* bhp = whi + ((size_t)(kb / 32) * 4 * 64 + l) * 8;
    const unsigned short* blp = wlo + ((size_t)(kb / 32) * 4 * 64 + l) * 8;

    f32x4 acc[2][4];
#pragma unroll
    for (int m = 0; m < 2; m++)
#pragma unroll
        for (int t = 0; t < 4; t++) acc[m][t] = f32x4{0, 0, 0, 0};

    float xf[2][2][8];                  // [buf][mtile][elem]
    *(float4*)&xf[0][0][0] = *(const float4*)(xp0);
    *(float4*)&xf[0][0][4] = *(const float4*)(xp0 + 4);
    *(float4*)&xf[0][1][0] = *(const float4*)(xp1);
    *(float4*)&xf[0][1][4] = *(const float4*)(xp1 + 4);

    for (int s = 0; s < KSTEPS; s++) {
        const int cur = s & 1, nxt = cur ^ 1;

        bf16x8 bh[4], bl[4];
        const unsigned short* bhs = bhp + (size_t)s * 4 * 64 * 8;
        const unsigned short* bls = blp + (size_t)s * 4 * 64 * 8;
#pragma unroll
        for (int t = 0; t < 4; t++) {
            bh[t] = *(const bf16x8*)(bhs + (size_t)t * 64 * 8);
            bl[t] = *(const bf16x8*)(bls + (size_t)t * 64 * 8);
        }

        if (s + 1 < KSTEPS) {           // prefetch next step's x (HBM)
            const float* xn0 = xp0 + (s + 1) * 32;
            const float* xn1 = xp1 + (s + 1) * 32;
            *(float4*)&xf[nxt][0][0] = *(const float4*)(xn0);
            *(float4*)&xf[nxt][0][4] = *(const float4*)(xn0 + 4);
            *(float4*)&xf[nxt][1][0] = *(const float4*)(xn1);
            *(float4*)&xf[nxt][1][4] = *(const float4*)(xn1 + 4);
        }

        bf16x8 ah[2], al[2];
        split8(xf[cur][0], ah[0], al[0]);
        split8(xf[cur][1], ah[1], al[1]);
#pragma unroll
        for (int m = 0; m < 2; m++)
#pragma unroll
            for (int t = 0; t < 4; t++) {
                acc[m][t] = __builtin_amdgcn_mfma_f32_16x16x32_bf16(ah[m], bh[t], acc[m][t], 0, 0, 0);
                acc[m][t] = __builtin_amdgcn_mfma_f32_16x16x32_bf16(ah[m], bl[t], acc[m][t], 0, 0, 0);
                acc[m][t] = __builtin_amdgcn_mfma_f32_16x16x32_bf16(al[m], bh[t], acc[m][t], 0, 0, 0);
            }
    }

    // C/D: row = q*4 + r, col = l&15  (m89-verified mapping)
    // Fire-and-forget HW f32 atomics; 16 lanes (col) contiguous per (m,t,r).
#pragma unroll
    for (int m = 0; m < 2; m++)
#pragma unroll
        for (int t = 0; t < 4; t++)
#pragma unroll
            for (int r = 0; r < 4; r++)
                unsafeAtomicAdd(
                    &logits[(size_t)(r0 + m * 16 + q * 4 + r) * NEXP + t * 16 + col],
                    acc[m][t][r]);

    // ---- split-K completion: last arriver for this row-block does the gate ----
    __syncthreads();                    // per-wave vmcnt(0) drain: block's atomics done
    if (tid == 0) {
        __threadfence();                // release: make adds visible device-wide
        const unsigned old = __hip_atomic_fetch_add(
            &cnt[blockIdx.x], 1u, __ATOMIC_ACQ_REL, __HIP_MEMORY_SCOPE_AGENT);
        last_flag = (old == KSPLIT - 1);
    }
    __syncthreads();
    if (!last_flag) return;

    // Gate for rows rbase..rbase+127: wave wv handles 32 rows, lane l = expert.
    const int rbase = blockIdx.x * 128;
    const float be  = bias[l];
    for (int c = 0; c < 4; c++) {
        float lv[8];                    // batch 8 coherent loads to pipeline latency
#pragma unroll
        for (int j = 0; j < 8; j++)
            lv[j] = __hip_atomic_load(
                &logits[(size_t)(rbase + wv * 32 + c * 8 + j) * NEXP + l],
                __ATOMIC_RELAXED, __HIP_MEMORY_SCOPE_AGENT);
#pragma unroll
        for (int j = 0; j < 8; j++) {
            const int row = rbase + wv * 32 + c * 8 + j;
            const float score = 1.0f / (1.0f + expf(-lv[j]));
            out[(size_t)4 * NROWS + (size_t)row * NEXP + l] = score;   // scores

            const float biased = score + be;

            float v = biased; int bi = l;
#pragma unroll
            for (int off = 32; off; off >>= 1) {
                const float ov = __shfl_xor(v, off);
                const int   oi = __shfl_xor(bi, off);
                if (ov > v || (ov == v && oi < bi)) { v = ov; bi = oi; }
            }
            const int i1 = bi;

            float v2 = (l == i1) ? -INFINITY : biased;
            int bi2 = l;
#pragma unroll
            for (int off = 32; off; off >>= 1) {
                const float ov = __shfl_xor(v2, off);
                const int   oi = __shfl_xor(bi2, off);
                if (ov > v2 || (ov == v2 && oi < bi2)) { v2 = ov; bi2 = oi; }
            }
            const int i2 = bi2;

            const float s1 = __shfl(score, i1);
            const float s2 = __shfl(score, i2);
            if (l == 0) {
                const float inv = 1.0f / (s1 + s2);
                out[(size_t)row * 2 + 0] = s1 * inv;
                out[(size_t)row * 2 + 1] = s2 * inv;
                out[(size_t)2 * NROWS + row * 2 + 0] = (float)i1;
                out[(size_t)2 * NROWS + row * 2 + 1] = (float)i2;
            }
        }
    }
}

extern "C" void kernel_launch(void* const* d_in, const int* in_sizes, int n_in,
                              void* d_out, int out_size, void* d_ws, size_t ws_size,
                              hipStream_t stream)
{
    const float* x    = (const float*)d_in[0];
    const float* w    = (const float*)d_in[1];
    const float* bias = (const float*)d_in[2];
    float* out  = (float*)d_out;

    float* logits = (float*)d_ws;                               // 2 MB
    const size_t logits_bytes = (size_t)NROWS * NEXP * 4;
    unsigned short* whi = (unsigned short*)((char*)d_ws + logits_bytes);  // 512 KB
    unsigned short* wlo = whi + (size_t)NEXP * DDIM;                      // 512 KB
    unsigned* cnt = (unsigned*)(wlo + (size_t)NEXP * DDIM);               // 256 B

    wfrag_kernel<<<DDIM / 32, 256, 0, stream>>>(w, whi, wlo, logits, cnt);
    dim3 g1(NROWS / 128, KSPLIT);
    gemm_gate_kernel<<<g1, 256, 0, stream>>>(x, whi, wlo, bias, logits, cnt, out);
}

// Round 3
// 217.772 us; speedup vs baseline: 1.6072x; 1.6072x over previous
//
#include <hip/hip_runtime.h>
#include <hip/hip_bf16.h>
#include <math.h>

#define NROWS 8192
#define DDIM  4096
#define NEXP  64
#define KSPLIT 16
#define KCHUNK (DDIM / KSPLIT)   // 256
#define KSTEPS (KCHUNK / 32)     // 8  -- compile-time: allocator pipelines it

typedef __attribute__((ext_vector_type(8))) short bf16x8;
typedef __attribute__((ext_vector_type(4))) float f32x4;

__device__ inline unsigned short bf16_rne(float f) {
    unsigned u = __builtin_bit_cast(unsigned, f);
    u += 0x7FFF + ((u >> 16) & 1);
    return (unsigned short)(u >> 16);
}

// split 8 fp32 -> hi/lo bf16 (x = hi + lo + r, |r| <= 2^-18|x|)
__device__ inline void split8(const float* xf, bf16x8& hi, bf16x8& lo) {
#pragma unroll
    for (int j = 0; j < 8; j++) {
        const unsigned short h = bf16_rne(xf[j]);
        const float hf = __builtin_bit_cast(float, (unsigned)h << 16);
        hi[j] = (short)h;
        lo[j] = (short)bf16_rne(xf[j] - hf);
    }
}

// Preconvert W (64 x 4096 fp32) into MFMA B-fragment-linear bf16 hi/lo:
// frag elem j of lane l, tile t, k-chunk kc = B[k=kc*32+(l>>4)*8+j][n=t*16+(l&15)]
// at ((kc*4+t)*64+l)*8. ~1 MB total -> L2/L3-resident for the GEMM.
// ALSO zeroes the 2 MB logits accumulator (ws is poisoned every iteration,
// and the GEMM accumulates into it with atomics).
__global__ __launch_bounds__(256) void wfrag_kernel(
    const float* __restrict__ w, unsigned short* __restrict__ whi,
    unsigned short* __restrict__ wlo, float* __restrict__ logits)
{
    const int kc = blockIdx.x;            // 0..127
    const int t  = threadIdx.x >> 6;      // n-tile 0..3
    const int l  = threadIdx.x & 63;
    const int e  = t * 16 + (l & 15);
    const int k0 = kc * 32 + ((l >> 4) * 8);
    const float* p = w + (size_t)e * DDIM + k0;
    float xf[8];
    *(float4*)&xf[0] = *(const float4*)p;
    *(float4*)&xf[4] = *(const float4*)(p + 4);
    bf16x8 hi, lo;
    split8(xf, hi, lo);
    const size_t off = ((size_t)(kc * 4 + t) * 64 + l) * 8;
    *(bf16x8*)(whi + off) = hi;
    *(bf16x8*)(wlo + off) = lo;

    // zero logits: 8192*64 floats = 131072 float4; 128 blk * 256 thr * 4 = 131072
    const float4 z = {0.f, 0.f, 0.f, 0.f};
    float4* lz = (float4*)logits;
    const int base = (blockIdx.x * 256 + threadIdx.x) * 4;
#pragma unroll
    for (int j = 0; j < 4; j++) lz[base + j] = z;
}

// GEMM: no LDS/barriers. Block = 4 waves; wave = 32 rows (2 m-tiles) x 64
// experts -> each B fragment feeds 2 MFMAs (B L2 traffic halved vs 16-row).
// ALL trip counts compile-time (R7 lesson: runtime ksplit made the allocator
// squeeze to 56 VGPR and spill 120 MB of scratch; R2-fused-gate lesson: ANY
// epilogue that adds barriers/flags re-triggers the squeeze -- 72 VGPR,
// 209 us. Keep this kernel's tail minimal: atomics only, no sync).
// Per k32-step: 4 x-loads (HBM/L3, double-buffered, issued FIRST -- longest
// latency) + 8 B-loads (L2, single-buffered, hidden behind split8 VALU)
// + 24 MFMA. Live set ~124 regs.
// Epilogue: split-K partials accumulated with HW f32 atomics into the 2 MB
// logits buffer (16 updates/address, LLC-resident) instead of a 32 MB
// materialized part[] round-trip (-64 MB HBM traffic vs R0).
__global__ __launch_bounds__(256) void gemm_partial_kernel(
    const float* __restrict__ x, const unsigned short* __restrict__ whi,
    const unsigned short* __restrict__ wlo, float* __restrict__ logits)
{
    const int tid = threadIdx.x;
    const int wv  = tid >> 6;
    const int l   = tid & 63;
    const int q   = l >> 4;
    const int col = l & 15;
    const int r0  = blockIdx.x * 128 + wv * 32;
    const int kh  = blockIdx.y;
    const int kb  = kh * KCHUNK;

    const float* xp0 = x + (size_t)(r0 + col) * DDIM + kb + q * 8;
    const float* xp1 = xp0 + (size_t)16 * DDIM;
    const unsigned short* bhp = whi + ((size_t)(kb / 32) * 4 * 64 + l) * 8;
    const unsigned short* blp = wlo + ((size_t)(kb / 32) * 4 * 64 + l) * 8;

    f32x4 acc[2][4];
#pragma unroll
    for (int m = 0; m < 2; m++)
#pragma unroll
        for (int t = 0; t < 4; t++) acc[m][t] = f32x4{0, 0, 0, 0};

    float xf[2][2][8];                  // [buf][mtile][elem]
    *(float4*)&xf[0][0][0] = *(const float4*)(xp0);
    *(float4*)&xf[0][0][4] = *(const float4*)(xp0 + 4);
    *(float4*)&xf[0][1][0] = *(const float4*)(xp1);
    *(float4*)&xf[0][1][4] = *(const float4*)(xp1 + 4);

    for (int s = 0; s < KSTEPS; s++) {
        const int cur = s & 1, nxt = cur ^ 1;

        if (s + 1 < KSTEPS) {           // prefetch next step's x first (HBM/L3,
            const float* xn0 = xp0 + (s + 1) * 32;   // longest latency)
            const float* xn1 = xp1 + (s + 1) * 32;
            *(float4*)&xf[nxt][0][0] = *(const float4*)(xn0);
            *(float4*)&xf[nxt][0][4] = *(const float4*)(xn0 + 4);
            *(float4*)&xf[nxt][1][0] = *(const float4*)(xn1);
            *(float4*)&xf[nxt][1][4] = *(const float4*)(xn1 + 4);
        }

        bf16x8 bh[4], bl[4];
        const unsigned short* bhs = bhp + (size_t)s * 4 * 64 * 8;
        const unsigned short* bls = blp + (size_t)s * 4 * 64 * 8;
#pragma unroll
        for (int t = 0; t < 4; t++) {
            bh[t] = *(const bf16x8*)(bhs + (size_t)t * 64 * 8);
            bl[t] = *(const bf16x8*)(bls + (size_t)t * 64 * 8);
        }

        bf16x8 ah[2], al[2];
        split8(xf[cur][0], ah[0], al[0]);
        split8(xf[cur][1], ah[1], al[1]);
#pragma unroll
        for (int m = 0; m < 2; m++)
#pragma unroll
            for (int t = 0; t < 4; t++) {
                acc[m][t] = __builtin_amdgcn_mfma_f32_16x16x32_bf16(ah[m], bh[t], acc[m][t], 0, 0, 0);
                acc[m][t] = __builtin_amdgcn_mfma_f32_16x16x32_bf16(ah[m], bl[t], acc[m][t], 0, 0, 0);
                acc[m][t] = __builtin_amdgcn_mfma_f32_16x16x32_bf16(al[m], bh[t], acc[m][t], 0, 0, 0);
            }
    }

    // C/D: row = q*4 + r, col = l&15  (m89-verified mapping)
    // Fire-and-forget HW f32 atomics; 16 lanes (col) contiguous per (m,t,r)
    // -> 64 B coalesced atomic bursts.
#pragma unroll
    for (int m = 0; m < 2; m++)
#pragma unroll
        for (int t = 0; t < 4; t++)
#pragma unroll
            for (int r = 0; r < 4; r++)
                unsafeAtomicAdd(
                    &logits[(size_t)(r0 + m * 16 + q * 4 + r) * NEXP + t * 16 + col],
                    acc[m][t][r]);
}

// One wave per row: load logit, sigmoid, +bias, top-2 (tie -> lower index),
// normalize. Kernel boundary after the GEMM provides cross-XCD coherence for
// the plain logits loads (verified passing in R1).
// out: [weights 2N][indices-as-float 2N][scores 64N]
__global__ __launch_bounds__(256) void gate_topk_kernel(
    const float* __restrict__ logits, const float* __restrict__ bias,
    float* __restrict__ out)
{
    const int tid = threadIdx.x;
    const int e   = tid & 63;
    const int row = blockIdx.x * 4 + (tid >> 6);
    const size_t idx = (size_t)row * NEXP + e;

    const float be    = bias[e];        // issue before logit load (L2/L3 hit)
    const float logit = logits[idx];
    const float score = 1.0f / (1.0f + expf(-logit));
    out[(size_t)4 * NROWS + idx] = score;           // scores

    const float biased = score + be;

    float v = biased; int bi = e;
#pragma unroll
    for (int off = 32; off; off >>= 1) {
        const float ov = __shfl_xor(v, off);
        const int   oi = __shfl_xor(bi, off);
        if (ov > v || (ov == v && oi < bi)) { v = ov; bi = oi; }
    }
    const int i1 = bi;

    float v2 = (e == i1) ? -INFINITY : biased;
    int bi2 = e;
#pragma unroll
    for (int off = 32; off; off >>= 1) {
        const float ov = __shfl_xor(v2, off);
        const int   oi = __shfl_xor(bi2, off);
        if (ov > v2 || (ov == v2 && oi < bi2)) { v2 = ov; bi2 = oi; }
    }
    const int i2 = bi2;

    const float s1 = __shfl(score, i1);
    const float s2 = __shfl(score, i2);
    if (e == 0) {
        const float inv = 1.0f / (s1 + s2);
        out[(size_t)row * 2 + 0] = s1 * inv;
        out[(size_t)row * 2 + 1] = s2 * inv;
        out[(size_t)2 * NROWS + row * 2 + 0] = (float)i1;
        out[(size_t)2 * NROWS + row * 2 + 1] = (float)i2;
    }
}

extern "C" void kernel_launch(void* const* d_in, const int* in_sizes, int n_in,
                              void* d_out, int out_size, void* d_ws, size_t ws_size,
                              hipStream_t stream)
{
    const float* x    = (const float*)d_in[0];
    const float* w    = (const float*)d_in[1];
    const float* bias = (const float*)d_in[2];
    float* out  = (float*)d_out;

    float* logits = (float*)d_ws;                               // 2 MB
    const size_t logits_bytes = (size_t)NROWS * NEXP * 4;
    unsigned short* whi = (unsigned short*)((char*)d_ws + logits_bytes);  // 512 KB
    unsigned short* wlo = whi + (size_t)NEXP * DDIM;                      // 512 KB

    wfrag_kernel<<<DDIM / 32, 256, 0, stream>>>(w, whi, wlo, logits);
    dim3 g1(NROWS / 128, KSPLIT);
    gemm_partial_kernel<<<g1, 256, 0, stream>>>(x, whi, wlo, logits);
    gate_topk_kernel<<<NROWS / 4, 256, 0, stream>>>(logits, bias, out);
}

// Round 5
// 213.708 us; speedup vs baseline: 1.6378x; 1.0190x over previous
//
#include <hip/hip_runtime.h>
#include <hip/hip_bf16.h>
#include <math.h>

#define NROWS 8192
#define DDIM  4096
#define NEXP  64
#define KSPLIT 16
#define KCHUNK (DDIM / KSPLIT)   // 256
#define KSTEPS (KCHUNK / 32)     // 8  -- compile-time: allocator pipelines it

typedef __attribute__((ext_vector_type(8))) short bf16x8;
typedef __attribute__((ext_vector_type(4))) float f32x4;

__device__ inline unsigned short bf16_rne(float f) {
    unsigned u = __builtin_bit_cast(unsigned, f);
    u += 0x7FFF + ((u >> 16) & 1);
    return (unsigned short)(u >> 16);
}

// split 8 fp32 -> hi/lo bf16 (x = hi + lo + r, |r| <= 2^-18|x|)
__device__ inline void split8(const float* xf, bf16x8& hi, bf16x8& lo) {
#pragma unroll
    for (int j = 0; j < 8; j++) {
        const unsigned short h = bf16_rne(xf[j]);
        const float hf = __builtin_bit_cast(float, (unsigned)h << 16);
        hi[j] = (short)h;
        lo[j] = (short)bf16_rne(xf[j] - hf);
    }
}

// Preconvert W (64 x 4096 fp32) into MFMA B-fragment-linear bf16 hi/lo:
// frag elem j of lane l, tile t, k-chunk kc = B[k=kc*32+(l>>4)*8+j][n=t*16+(l&15)]
// at ((kc*4+t)*64+l)*8. ~1 MB total -> L2/L3-resident for the GEMM.
// ALSO zeroes the 2 MB logits accumulator (ws is poisoned every iteration,
// and the GEMM accumulates into it with atomics).
__global__ __launch_bounds__(256) void wfrag_kernel(
    const float* __restrict__ w, unsigned short* __restrict__ whi,
    unsigned short* __restrict__ wlo, float* __restrict__ logits)
{
    const int kc = blockIdx.x;            // 0..127
    const int t  = threadIdx.x >> 6;      // n-tile 0..3
    const int l  = threadIdx.x & 63;
    const int e  = t * 16 + (l & 15);
    const int k0 = kc * 32 + ((l >> 4) * 8);
    const float* p = w + (size_t)e * DDIM + k0;
    float xf[8];
    *(float4*)&xf[0] = *(const float4*)p;
    *(float4*)&xf[4] = *(const float4*)(p + 4);
    bf16x8 hi, lo;
    split8(xf, hi, lo);
    const size_t off = ((size_t)(kc * 4 + t) * 64 + l) * 8;
    *(bf16x8*)(whi + off) = hi;
    *(bf16x8*)(wlo + off) = lo;

    // zero logits: 8192*64 floats = 131072 float4; 128 blk * 256 thr * 4 = 131072
    const float4 z = {0.f, 0.f, 0.f, 0.f};
    float4* lz = (float4*)logits;
    const int base = (blockIdx.x * 256 + threadIdx.x) * 4;
#pragma unroll
    for (int j = 0; j < 4; j++) lz[base + j] = z;
}

// GEMM: block = 4 waves; wave = 32 rows (2 m-tiles) x 64 experts.
// x is staged through WAVE-PRIVATE LDS (no barriers -- each wave's 32 rows
// are disjoint, so no cross-wave sync; avoids the R2 fused-gate register-
// squeeze trap). Stage via global_load_lds width=16: each instr loads 8 rows
// x 128 B fully contiguous (16 lines/instr, 100% line use, vs the old
// register path's 32 scattered half-used lines). Source addrs pre-swizzled
// (slot ^= row&7; guide rule #21: linear LDS dest + inverse-swz source +
// swz read) so ds_read_b128 fragment reads are bank-uniform.
// Double-buffered 4 KB/wave; counted wait: exactly 8 B-loads issue between
// stage_s and wait_s -> s_waitcnt vmcnt(8); sched_barrier(0) pins each
// stage block AND the wait itself (rule #18 class) so the count is robust.
// Removing the xf VGPR double-buffer frees ~32 regs of pressure.
// Epilogue: fire-and-forget HW f32 atomics into the 2 MB logits buffer
// (16 updates/address, LLC-resident). No sync after (R2 lesson).
__global__ __launch_bounds__(256) void gemm_partial_kernel(
    const float* __restrict__ x, const unsigned short* __restrict__ whi,
    const unsigned short* __restrict__ wlo, float* __restrict__ logits)
{
    __shared__ float ldsx[4 * 2 * 1024];   // [wave][buf][32 rows x 32 floats] = 32 KB

    const int tid = threadIdx.x;
    const int wv  = tid >> 6;
    const int l   = tid & 63;
    const int q   = l >> 4;
    const int col = l & 15;
    const int c7  = col & 7;
    const int r0  = blockIdx.x * 128 + wv * 32;
    const int kb  = blockIdx.y * KCHUNK;

    // stage mapping: instr g stages local rows g*8..g*8+7, 128 B each.
    // lane i -> row g*8 + (i>>3), phys slot i&7, sourced from logical slot
    // (i&7) ^ (row&7)  (inverse swizzle on the global address).
    const int slr   = l >> 3;
    const int slotp = l & 7;

    float* ldsw = ldsx + wv * 2048;        // this wave's two 1024-float bufs

    const unsigned short* bhp = whi + ((size_t)(kb / 32) * 4 * 64 + l) * 8;
    const unsigned short* blp = wlo + ((size_t)(kb / 32) * 4 * 64 + l) * 8;

    f32x4 acc[2][4];
#pragma unroll
    for (int m = 0; m < 2; m++)
#pragma unroll
        for (int t = 0; t < 4; t++) acc[m][t] = f32x4{0, 0, 0, 0};

    auto STAGE = [&](int buf, int s) {
#pragma unroll
        for (int g = 0; g < 4; g++) {
            const int lr   = g * 8 + slr;
            const int slot = slotp ^ (lr & 7);
            const float* gp = x + (size_t)(r0 + lr) * DDIM + kb + s * 32 + slot * 4;
            __builtin_amdgcn_global_load_lds(
                (const __attribute__((address_space(1))) void*)gp,
                (__attribute__((address_space(3))) void*)(ldsw + buf * 1024 + g * 256),
                16, 0, 0);
        }
    };

    STAGE(0, 0);
    __builtin_amdgcn_sched_barrier(0);     // pin stage block (wait-count integrity)

    for (int s = 0; s < KSTEPS; s++) {
        const int buf = s & 1;

        // B loads for this step (exactly 8 dwordx4, L2-resident)
        bf16x8 bh[4], bl[4];
        const unsigned short* bhs = bhp + (size_t)s * 4 * 64 * 8;
        const unsigned short* bls = blp + (size_t)s * 4 * 64 * 8;
#pragma unroll
        for (int t = 0; t < 4; t++) {
            bh[t] = *(const bf16x8*)(bhs + (size_t)t * 64 * 8);
            bl[t] = *(const bf16x8*)(bls + (size_t)t * 64 * 8);
        }

        // ops issued since stage(buf) finished issuing: exactly the 8 B-loads
        // above -> vmcnt(8) guarantees stage(buf) landed in LDS (in-order
        // vmcnt retirement), while keeping the 8 B-loads in flight.
        asm volatile("s_waitcnt vmcnt(8)" ::: "memory");
        __builtin_amdgcn_sched_barrier(0); // nothing crosses the wait (rule #18)

        // read this wave's fragments from LDS (swizzled, bank-uniform b128)
        float xr[2][8];
#pragma unroll
        for (int m = 0; m < 2; m++) {
            const float* rb = ldsw + buf * 1024 + (m * 16 + col) * 32;
            const int sp0 = (q * 2) ^ c7;
            *(float4*)&xr[m][0] = *(const float4*)(rb + sp0 * 4);
            *(float4*)&xr[m][4] = *(const float4*)(rb + (sp0 ^ 1) * 4);
        }

        // prefetch next step into the other buffer (wrap at s=7 is a harmless
        // dead re-stage of step 0 -- keeps the wait count uniform)
        STAGE(buf ^ 1, (s + 1) & 7);
        __builtin_amdgcn_sched_barrier(0);

        bf16x8 ah[2], al[2];
        split8(xr[0], ah[0], al[0]);
        split8(xr[1], ah[1], al[1]);
#pragma unroll
        for (int m = 0; m < 2; m++)
#pragma unroll
            for (int t = 0; t < 4; t++) {
                acc[m][t] = __builtin_amdgcn_mfma_f32_16x16x32_bf16(ah[m], bh[t], acc[m][t], 0, 0, 0);
                acc[m][t] = __builtin_amdgcn_mfma_f32_16x16x32_bf16(ah[m], bl[t], acc[m][t], 0, 0, 0);
                acc[m][t] = __builtin_amdgcn_mfma_f32_16x16x32_bf16(al[m], bh[t], acc[m][t], 0, 0, 0);
            }
    }

    // C/D: row = q*4 + r, col = l&15  (m89-verified mapping)
    // Fire-and-forget HW f32 atomics; 16 lanes (col) contiguous per (m,t,r).
#pragma unroll
    for (int m = 0; m < 2; m++)
#pragma unroll
        for (int t = 0; t < 4; t++)
#pragma unroll
            for (int r = 0; r < 4; r++)
                unsafeAtomicAdd(
                    &logits[(size_t)(r0 + m * 16 + q * 4 + r) * NEXP + t * 16 + col],
                    acc[m][t][r]);
}

// One wave per row: load logit, sigmoid, +bias, top-2 (tie -> lower index),
// normalize. Kernel boundary after the GEMM provides cross-XCD coherence for
// the plain logits loads (verified passing in R1/R3).
// out: [weights 2N][indices-as-float 2N][scores 64N]
__global__ __launch_bounds__(256) void gate_topk_kernel(
    const float* __restrict__ logits, const float* __restrict__ bias,
    float* __restrict__ out)
{
    const int tid = threadIdx.x;
    const int e   = tid & 63;
    const int row = blockIdx.x * 4 + (tid >> 6);
    const size_t idx = (size_t)row * NEXP + e;

    const float be    = bias[e];        // issue before logit load
    const float logit = logits[idx];
    const float score = 1.0f / (1.0f + expf(-logit));
    out[(size_t)4 * NROWS + idx] = score;           // scores

    const float biased = score + be;

    float v = biased; int bi = e;
#pragma unroll
    for (int off = 32; off; off >>= 1) {
        const float ov = __shfl_xor(v, off);
        const int   oi = __shfl_xor(bi, off);
        if (ov > v || (ov == v && oi < bi)) { v = ov; bi = oi; }
    }
    const int i1 = bi;

    float v2 = (e == i1) ? -INFINITY : biased;
    int bi2 = e;
#pragma unroll
    for (int off = 32; off; off >>= 1) {
        const float ov = __shfl_xor(v2, off);
        const int   oi = __shfl_xor(bi2, off);
        if (ov > v2 || (ov == v2 && oi < bi2)) { v2 = ov; bi2 = oi; }
    }
    const int i2 = bi2;

    const float s1 = __shfl(score, i1);
    const float s2 = __shfl(score, i2);
    if (e == 0) {
        const float inv = 1.0f / (s1 + s2);
        out[(size_t)row * 2 + 0] = s1 * inv;
        out[(size_t)row * 2 + 1] = s2 * inv;
        out[(size_t)2 * NROWS + row * 2 + 0] = (float)i1;
        out[(size_t)2 * NROWS + row * 2 + 1] = (float)i2;
    }
}

extern "C" void kernel_launch(void* const* d_in, const int* in_sizes, int n_in,
                              void* d_out, int out_size, void* d_ws, size_t ws_size,
                              hipStream_t stream)
{
    const float* x    = (const float*)d_in[0];
    const float* w    = (const float*)d_in[1];
    const float* bias = (const float*)d_in[2];
    float* out  = (float*)d_out;

    float* logits = (float*)d_ws;                               // 2 MB
    const size_t logits_bytes = (size_t)NROWS * NEXP * 4;
    unsigned short* whi = (unsigned short*)((char*)d_ws + logits_bytes);  // 512 KB
    unsigned short* wlo = whi + (size_t)NEXP * DDIM;                      // 512 KB

    wfrag_kernel<<<DDIM / 32, 256, 0, stream>>>(w, whi, wlo, logits);
    dim3 g1(NROWS / 128, KSPLIT);
    gemm_partial_kernel<<<g1, 256, 0, stream>>>(x, whi, wlo, logits);
    gate_topk_kernel<<<NROWS / 4, 256, 0, stream>>>(logits, bias, out);
}